// Round 17
// baseline (16008.110 us; speedup 1.0000x reference)
//
#include <hip/hip_runtime.h>
#include <math.h>

// ESN reservoir, persistent kernel, round 17.
// h_t = tanh(x_t Win^T + h_{t-1} W^T); out_t = h_t Wout^T + b
//
// r16 (7.65ms, matched model): int8 W fully in 128KB LDS + sdot4; int8 h
// exchange (1MB/step). Step 3.73us @ VALUBusy 20.6% -> chain is latency +
// epilogue serialization (5 barriers/step; wave-0-only pack/store/drain).
// r17 = ONE conceptual change: wave-autonomous epilogue, 5 barriers -> 1.
//  - hs double-buffered (2x4KB): kills pre-stage + post-compute syncs;
//    1-step wave skew safe (parity buffers; gate includes own block's flag).
//  - per-wave transpose-reduce in red[w]: same-wave LDS, no barrier.
//  - each wave packs (shfl) + stores its own 4 strip dwords, drains its own
//    s_waitcnt(0), then LDS atomicAdd; 8th wave emits the block flag
//    (r12 transitive-visibility discipline preserved).
//  - wave 0 gates (r16-exact) and releases staging waves via LDS go-word.
// Compute/quant/gate/addresses/projection: r16-identical. Spins bounded.

#define RDIM   2048
#define BATCH  16
#define TSTEPS 2048
#define NIN    3
#define NOUT   3
#define NBLK   256
#define NTHR   512

#define HB_BYTES  (BATCH * RDIM)             // 32 KB per h buffer (int8)
#define OFF_H0_B  0
#define OFF_H1_B  (HB_BYTES)
#define OFF_FLAGS ((2 * HB_BYTES) / 4)       // dword index: 256 dwords
#define WS_USED_DW (OFF_FLAGS + 256)
#define SPIN_MAX  (1L << 20)

#define CPOL_SC0_SC1 0x11                    // UC: read at coherence point

__device__ __forceinline__ void load_lds16(const void* g, void* l) {
    __builtin_amdgcn_global_load_lds(
        (const __attribute__((address_space(1))) void*)g,
        (__attribute__((address_space(3))) void*)l, 16, 0, CPOL_SC0_SC1);
}

__device__ __forceinline__ unsigned sysld(const unsigned* p) {
    return __hip_atomic_load(p, __ATOMIC_RELAXED, __HIP_MEMORY_SCOPE_SYSTEM);
}
__device__ __forceinline__ void sysst(unsigned* p, unsigned v) {
    __hip_atomic_store(p, v, __ATOMIC_RELAXED, __HIP_MEMORY_SCOPE_SYSTEM);
}

__device__ __forceinline__ int q8(float v) {          // round, clamp [-127,127]
    float c = fminf(127.f, fmaxf(-127.f, v));
    return (int)__builtin_rintf(c);
}
__device__ __forceinline__ unsigned pack4(int a, int b, int c, int d) {
    return (a & 0xff) | ((b & 0xff) << 8) | ((c & 0xff) << 16) | ((d & 0xff) << 24);
}

__device__ __forceinline__ int dot4i(unsigned a, unsigned b, int c) {
#if __has_builtin(__builtin_amdgcn_sdot4)
    return __builtin_amdgcn_sdot4((int)a, (int)b, c, false);
#else
    c += (int)(signed char)(a) * (int)(signed char)(b);
    c += (int)(signed char)(a >> 8)  * (int)(signed char)(b >> 8);
    c += (int)(signed char)(a >> 16) * (int)(signed char)(b >> 16);
    c += (int)(signed char)(a >> 24) * (int)(signed char)(b >> 24);
    return c;
#endif
}
__device__ __forceinline__ int dot16(uint4 wq, uint4 hq, int c) {
    c = dot4i(wq.x, hq.x, c);
    c = dot4i(wq.y, hq.y, c);
    c = dot4i(wq.z, hq.z, c);
    c = dot4i(wq.w, hq.w, c);
    return c;
}

extern "C" __global__ void __launch_bounds__(NTHR, 1) esn_persist(
    const float* __restrict__ W,       // [R,R] fp32
    const float* __restrict__ Win,     // [R,3]
    const float* __restrict__ x,       // [B,T,3]
    const float* __restrict__ Wout,    // [3,R]
    const float* __restrict__ bout,    // [3]
    unsigned char* hb0,                // [B][R] int8 (scale 1/127)
    unsigned char* hb1,
    unsigned* flags,                   // [256]
    float* __restrict__ out)           // [B,T,3]
{
    __shared__ unsigned hs_dw[2][1024];         // 2 x 4 KB: staged h, parity-buffered
    __shared__ int  red[8][544];                // per-wave transpose scratch
    __shared__ float wscale[64];                // per-row W scale (m/127)
    __shared__ unsigned go_lds;                 // gate->staging handshake
    __shared__ unsigned cnt;                    // epilogue completion counter
    extern __shared__ unsigned wlds[];          // 128 KB: W int8 [64 rows][512 dw]

    const int tid  = threadIdx.x;
    const int lane = tid & 63;
    const int w    = tid >> 6;                  // wave 0..7
    const int blk  = blockIdx.x;
    const int rg   = blk & 31;                  // rows rg*64..+64
    const int g    = blk >> 5;                  // batches g*2..+2
    const int rbase = rg * 64 + w * 8;          // wave's 8 rows
    const int b0    = g * 2;

    if (tid == 0) { go_lds = 0; cnt = 0; }

    // ---- one-time: quantize W rows -> LDS int8 (per-row scale), r16-exact ----
#pragma unroll
    for (int rr = 0; rr < 8; ++rr) {
        const int   row = rbase + rr;
        const float4* Wr = (const float4*)(W + (size_t)row * RDIM);
        float m = 0.f;
#pragma unroll
        for (int j = 0; j < 8; ++j) {
            float4 v = Wr[j * 64 + lane];
            m = fmaxf(m, fmaxf(fmaxf(fabsf(v.x), fabsf(v.y)),
                               fmaxf(fabsf(v.z), fabsf(v.w))));
        }
#pragma unroll
        for (int off = 32; off >= 1; off >>= 1)
            m = fmaxf(m, __shfl_xor(m, off, 64));
        const float inv = (m > 0.f) ? 127.f / m : 0.f;
        if (lane == 0) wscale[w * 8 + rr] = (m > 0.f) ? m / 127.f : 0.f;
#pragma unroll
        for (int j = 0; j < 8; ++j) {
            float4 v = Wr[j * 64 + lane];
            wlds[(w * 8 + rr) * 512 + j * 64 + lane] =
                pack4(q8(v.x * inv), q8(v.y * inv), q8(v.z * inv), q8(v.w * inv));
        }
    }
    __syncthreads();

    for (int t = 0; t <= TSTEPS; ++t) {
        const unsigned char* hprev = (t & 1) ? hb1 : hb0;
        unsigned char*       hnext = (t & 1) ? hb0 : hb1;
        unsigned*            hsbuf = hs_dw[t & 1];
        const unsigned       tgt   = (unsigned)t;

        // ---- wave 0: gate (r16-exact), then release staging waves ----
        if (w == 0) {
            if (t > 0) {
                long spins = 0;
                for (;;) {
                    unsigned vv = (lane < 32) ? sysld(&flags[g * 32 + lane]) : tgt;
                    if (__all((int)(vv >= tgt))) break;
                    if (spins > 64) __builtin_amdgcn_s_sleep(2);
                    if (++spins > SPIN_MAX) break;   // never hang
                }
            }
            if (lane == 0)
                __hip_atomic_store(&go_lds, (unsigned)(t + 1),
                                   __ATOMIC_RELEASE, __HIP_MEMORY_SCOPE_WORKGROUP);
        } else if (w < 4) {
            // staging waves wait on LDS go-word (no fabric traffic)
            if (lane == 0) {
                long spins = 0;
                while (__hip_atomic_load(&go_lds, __ATOMIC_ACQUIRE,
                                         __HIP_MEMORY_SCOPE_WORKGROUP) < (unsigned)(t + 1)) {
                    __builtin_amdgcn_s_sleep(1);
                    if (++spins > SPIN_MAX) break;
                }
            }
            // wave-local fence: all 64 lanes wait for lane 0's result
            __builtin_amdgcn_wave_barrier();
            (void)__shfl(0, 0, 64);   // no-op cross-lane to keep wave converged
        }

        // ---- stage h[b0..b0+1][:] int8 (4 KB) into parity buffer, waves 0-3 ----
        if (w < 4) {
            load_lds16(hprev + (size_t)g * 4096 + (size_t)(w * 64 + lane) * 16,
                       (char*)hsbuf + (size_t)(w * 64) * 16);
        }
        __syncthreads();   // THE one barrier: staging visible to all waves

        if (t < TSTEPS) {
            int acc[8][2];
#pragma unroll
            for (int r = 0; r < 8; ++r) { acc[r][0] = 0; acc[r][1] = 0; }

            const uint4* h4 = (const uint4*)hsbuf;
            uint4 hA0 = h4[lane];            // b0, k = 16*lane..+16
            uint4 hA1 = h4[64 + lane];       // b0, k = 1024+16*lane..+16
            uint4 hB0 = h4[128 + lane];      // b1
            uint4 hB1 = h4[192 + lane];

            const uint4* w4p = (const uint4*)wlds;
#pragma unroll
            for (int rr = 0; rr < 8; ++rr) {
                const int wb = (w * 8 + rr) * 128;
                uint4 w0 = w4p[wb + lane];
                uint4 w1 = w4p[wb + 64 + lane];
                acc[rr][0] = dot16(w0, hA0, acc[rr][0]);
                acc[rr][0] = dot16(w1, hA1, acc[rr][0]);
                acc[rr][1] = dot16(w0, hB0, acc[rr][1]);
                acc[rr][1] = dot16(w1, hB1, acc[rr][1]);
            }

            // ---- wave-local reduce: fold 32, transpose via red[w] (no barrier:
            //      same-wave LDS write->read, compiler-ordered lgkmcnt) ----
            int v[16];
#pragma unroll
            for (int i = 0; i < 16; ++i) {
                int a = acc[i >> 1][i & 1];
                v[i] = a + __shfl_xor(a, 32, 64);
            }
            if (lane < 32) {
#pragma unroll
                for (int i = 0; i < 16; ++i)
                    red[w][lane * 17 + ((i + lane) & 15)] = v[i];
            }
            int qv = 0;
            if (lane < 16) {
                int s = 0;
#pragma unroll
                for (int l = 0; l < 32; ++l)
                    s += red[w][l * 17 + ((lane + l) & 15)];
                const int r   = lane >> 1;          // 0..7
                const int b   = lane & 1;
                const int row = rbase + r;
                const int bg  = b0 + b;
                float pre = (float)s * wscale[w * 8 + r] * (1.f / 127.f);
#pragma unroll
                for (int c = 0; c < NIN; ++c)
                    pre += Win[row * NIN + c] * x[((size_t)bg * TSTEPS + t) * NIN + c];
                qv = q8(tanhf(pre) * 127.f);        // h value, quantized
            }

            // ---- per-wave strip pack (shfl) + store + drain + count ----
            // value for (local row r, batch b) sits in lane 2r+b (r<8).
            {
                const int pb = lane >> 1;           // packer: b (lanes 0..3)
                const int pd = lane & 1;            // packer: dword half
                unsigned pk = pack4(__shfl(qv, 8 * pd + 0 + pb, 64),
                                    __shfl(qv, 8 * pd + 2 + pb, 64),
                                    __shfl(qv, 8 * pd + 4 + pb, 64),
                                    __shfl(qv, 8 * pd + 6 + pb, 64));
                if (lane < 4) {
                    unsigned* dst = (unsigned*)(hnext + (size_t)(b0 + pb) * RDIM + rg * 64);
                    sysst(&dst[w * 2 + pd], pk);
                }
            }
            __builtin_amdgcn_s_waitcnt(0);          // this wave's strips acked
            if (lane == 0) {
                unsigned old = atomicAdd(&cnt, 1u); // LDS, returns pre-add
                if (old == 8u * (unsigned)(t + 1) - 1u)      // last wave of step
                    sysst(&flags[g * 32 + rg], (unsigned)(t + 1));
            }
        }

        // ---- projection of staged state by rotating block (off chain) ----
        if (t > 0 && rg == ((t - 1) & 31)) {
            const signed char* hsv = (const signed char*)hsbuf;
            const int o = t - 1;
            if (w < 6) {
                const int b = w / NOUT;             // 0..1
                const int k = w % NOUT;             // 0..2
                float a = 0.f;
#pragma unroll
                for (int j = 0; j < 32; ++j) {
                    const int r = j * 64 + lane;
                    a += (float)hsv[b * RDIM + r] * Wout[k * RDIM + r];
                }
#pragma unroll
                for (int off = 32; off >= 1; off >>= 1)
                    a += __shfl_xor(a, off, 64);
                if (lane == 0)
                    out[((size_t)(b0 + b) * TSTEPS + o) * NOUT + k] =
                        a * (1.f / 127.f) + bout[k];
            }
        }
    }
}

extern "C" void kernel_launch(void* const* d_in, const int* in_sizes, int n_in,
                              void* d_out, int out_size, void* d_ws, size_t ws_size,
                              hipStream_t stream) {
    const float* x    = (const float*)d_in[0];
    const float* Win  = (const float*)d_in[1];
    const float* W    = (const float*)d_in[2];
    const float* Wout = (const float*)d_in[3];
    const float* bout = (const float*)d_in[4];
    float* out = (float*)d_out;

    unsigned char* wsb = (unsigned char*)d_ws;
    unsigned char* hb0 = wsb + OFF_H0_B;
    unsigned char* hb1 = wsb + OFF_H1_B;
    unsigned*    flags = (unsigned*)d_ws + OFF_FLAGS;

    // zero h buffers (h0 = 0) + flags (~66 KB)
    hipMemsetAsync(d_ws, 0, (size_t)WS_USED_DW * sizeof(unsigned), stream);

    // allow 128 KB dynamic LDS (idempotent; same work every call)
    hipFuncSetAttribute((const void*)esn_persist,
                        hipFuncAttributeMaxDynamicSharedMemorySize, 131072);

    void* args[] = {(void*)&W, (void*)&Win, (void*)&x, (void*)&Wout, (void*)&bout,
                    (void*)&hb0, (void*)&hb1, (void*)&flags, (void*)&out};
    hipError_t e = hipLaunchCooperativeKernel((const void*)esn_persist,
                                              dim3(NBLK), dim3(NTHR),
                                              args, 131072, stream);
    if (e != hipSuccess) {
        // Fallback: plain launch (256 blocks, 1/CU with ~150KB LDS -> all
        // co-resident; bounded spins guarantee no hang regardless).
        esn_persist<<<dim3(NBLK), dim3(NTHR), 131072, stream>>>(
            W, Win, x, Wout, bout, hb0, hb1, flags, out);
    }
}

// Round 18
// 7632.352 us; speedup vs baseline: 2.0974x; 2.0974x over previous
//
#include <hip/hip_runtime.h>
#include <math.h>

// ESN reservoir, persistent kernel, round 18 = round 16 VERBATIM (best: 7.65ms).
// h_t = tanh(x_t Win^T + h_{t-1} W^T); out_t = h_t Wout^T + b
//
// r17's wave-parallel epilogue regressed 2.1x (8 per-wave UC store drains put
// max-of-8 tail latency on the chain; fragmented 8B stores). Reverting.
// Structure (r16):
//  - ALL of the block's W (64 rows x 2048) in 128KB dynamic LDS as int8,
//    per-row scale; no L2-W stream. h exchanged int8 (1MB/step).
//  - v_dot4_i32_i8 (sdot4), exact int32 accumulate, dequant in epilogue.
//  - block = 64 rows x 2 batches; 8 independent 32-block group gates;
//    wave-0 coalesced strip store + s_waitcnt(0) + flag (r12 discipline).
//  - bounded spins: worst case wrong answer, never a hang.

#define RDIM   2048
#define BATCH  16
#define TSTEPS 2048
#define NIN    3
#define NOUT   3
#define NBLK   256
#define NTHR   512

#define HB_BYTES  (BATCH * RDIM)             // 32 KB per h buffer (int8)
#define OFF_H0_B  0
#define OFF_H1_B  (HB_BYTES)
#define OFF_FLAGS ((2 * HB_BYTES) / 4)       // dword index: 256 dwords
#define WS_USED_DW (OFF_FLAGS + 256)
#define WLDS_DW   (64 * 512)                 // 32768 dwords = 128 KB int8 W
#define SPIN_MAX  (1L << 20)

#define CPOL_SC0_SC1 0x11                    // UC: read at coherence point

__device__ __forceinline__ void load_lds16(const void* g, void* l) {
    __builtin_amdgcn_global_load_lds(
        (const __attribute__((address_space(1))) void*)g,
        (__attribute__((address_space(3))) void*)l, 16, 0, CPOL_SC0_SC1);
}

__device__ __forceinline__ unsigned sysld(const unsigned* p) {
    return __hip_atomic_load(p, __ATOMIC_RELAXED, __HIP_MEMORY_SCOPE_SYSTEM);
}
__device__ __forceinline__ void sysst(unsigned* p, unsigned v) {
    __hip_atomic_store(p, v, __ATOMIC_RELAXED, __HIP_MEMORY_SCOPE_SYSTEM);
}

__device__ __forceinline__ int q8(float v) {          // round, clamp [-127,127]
    float c = fminf(127.f, fmaxf(-127.f, v));
    return (int)__builtin_rintf(c);
}
__device__ __forceinline__ unsigned pack4(int a, int b, int c, int d) {
    return (a & 0xff) | ((b & 0xff) << 8) | ((c & 0xff) << 16) | ((d & 0xff) << 24);
}

// dword(4xi8) dot dword(4xi8) + c, exact int32
__device__ __forceinline__ int dot4i(unsigned a, unsigned b, int c) {
#if __has_builtin(__builtin_amdgcn_sdot4)
    return __builtin_amdgcn_sdot4((int)a, (int)b, c, false);
#else
    c += (int)(signed char)(a) * (int)(signed char)(b);
    c += (int)(signed char)(a >> 8)  * (int)(signed char)(b >> 8);
    c += (int)(signed char)(a >> 16) * (int)(signed char)(b >> 16);
    c += (int)(signed char)(a >> 24) * (int)(signed char)(b >> 24);
    return c;
#endif
}
// 16-element int8 dot via uint4 (4 sdot4)
__device__ __forceinline__ int dot16(uint4 wq, uint4 hq, int c) {
    c = dot4i(wq.x, hq.x, c);
    c = dot4i(wq.y, hq.y, c);
    c = dot4i(wq.z, hq.z, c);
    c = dot4i(wq.w, hq.w, c);
    return c;
}

extern "C" __global__ void __launch_bounds__(NTHR, 1) esn_persist(
    const float* __restrict__ W,       // [R,R] fp32
    const float* __restrict__ Win,     // [R,3]
    const float* __restrict__ x,       // [B,T,3]
    const float* __restrict__ Wout,    // [3,R]
    const float* __restrict__ bout,    // [3]
    unsigned char* hb0,                // [B][R] int8 (scale 1/127)
    unsigned char* hb1,
    unsigned* flags,                   // [256]
    float* __restrict__ out)           // [B,T,3]
{
    __shared__ unsigned hs_dw[1024];            // 4 KB: staged h int8 [2][2048B]
    __shared__ int  red[8][544];                // transpose-reduce (int partials)
    __shared__ float hblk[64][2];               // 64 rows x 2 batches (float)
    __shared__ float wscale[64];                // per-row W scale (m/127)
    extern __shared__ unsigned wlds[];          // 128 KB: W int8 [64 rows][512 dw]

    const int tid  = threadIdx.x;
    const int lane = tid & 63;
    const int w    = tid >> 6;                  // wave 0..7
    const int blk  = blockIdx.x;
    const int rg   = blk & 31;                  // rows rg*64..+64
    const int g    = blk >> 5;                  // batches g*2..+2
    const int rbase = rg * 64 + w * 8;          // wave's 8 rows
    const int b0    = g * 2;

    // ---- one-time: quantize W rows -> LDS int8 (per-row scale) ----
#pragma unroll
    for (int rr = 0; rr < 8; ++rr) {
        const int   row = rbase + rr;
        const float4* Wr = (const float4*)(W + (size_t)row * RDIM);
        float m = 0.f;
#pragma unroll
        for (int j = 0; j < 8; ++j) {           // lane covers 8 float4 = 32 elems
            float4 v = Wr[j * 64 + lane];
            m = fmaxf(m, fmaxf(fmaxf(fabsf(v.x), fabsf(v.y)),
                               fmaxf(fabsf(v.z), fabsf(v.w))));
        }
#pragma unroll
        for (int off = 32; off >= 1; off >>= 1)
            m = fmaxf(m, __shfl_xor(m, off, 64));
        const float inv = (m > 0.f) ? 127.f / m : 0.f;
        if (lane == 0) wscale[w * 8 + rr] = (m > 0.f) ? m / 127.f : 0.f;
#pragma unroll
        for (int j = 0; j < 8; ++j) {
            float4 v = Wr[j * 64 + lane];
            wlds[(w * 8 + rr) * 512 + j * 64 + lane] =
                pack4(q8(v.x * inv), q8(v.y * inv), q8(v.z * inv), q8(v.w * inv));
        }
    }
    __syncthreads();

    for (int t = 0; t <= TSTEPS; ++t) {
        const unsigned char* hprev = (t & 1) ? hb1 : hb0;
        unsigned char*       hnext = (t & 1) ? hb0 : hb1;
        const unsigned       tgt   = (unsigned)t;

        // ---- one-hop gate: all 32 producers of my group at >= t ----
        if (t > 0 && w == 0) {
            long spins = 0;
            for (;;) {
                unsigned vv = (lane < 32) ? sysld(&flags[g * 32 + lane]) : tgt;
                if (__all((int)(vv >= tgt))) break;
                if (spins > 64) __builtin_amdgcn_s_sleep(2);  // fast-poll first
                if (++spins > SPIN_MAX) break;   // never hang
            }
        }
        __syncthreads();

        // ---- stage h[b0..b0+1][:] int8 (4 KB = 256 granules), waves 0-3 ----
        if (w < 4) {
            load_lds16(hprev + (size_t)g * 4096 + (size_t)(w * 64 + lane) * 16,
                       (char*)hs_dw + (size_t)(w * 64) * 16);
        }
        __syncthreads();   // staging complete (drains vmcnt)

        if (t < TSTEPS) {
            int acc[8][2];
#pragma unroll
            for (int r = 0; r < 8; ++r) { acc[r][0] = 0; acc[r][1] = 0; }

            // h granules: batch b0 at 0..127, b1 at 128..255 (16 k each)
            const uint4* h4 = (const uint4*)hs_dw;
            uint4 hA0 = h4[lane];            // b0, k = 16*lane..+16
            uint4 hA1 = h4[64 + lane];       // b0, k = 1024+16*lane..+16
            uint4 hB0 = h4[128 + lane];      // b1
            uint4 hB1 = h4[192 + lane];

            const uint4* w4p = (const uint4*)wlds;   // row r: 128 granules
#pragma unroll
            for (int rr = 0; rr < 8; ++rr) {
                const int wb = (w * 8 + rr) * 128;
                uint4 w0 = w4p[wb + lane];           // k = 16*lane..+16
                uint4 w1 = w4p[wb + 64 + lane];      // k = 1024+16*lane..+16
                acc[rr][0] = dot16(w0, hA0, acc[rr][0]);
                acc[rr][0] = dot16(w1, hA1, acc[rr][0]);
                acc[rr][1] = dot16(w0, hB0, acc[rr][1]);
                acc[rr][1] = dot16(w1, hB1, acc[rr][1]);
            }

            // ---- reduce: fold 32, swizzled transpose, sum 32 (int exact) ----
            int v[16];
#pragma unroll
            for (int i = 0; i < 16; ++i) {
                int a = acc[i >> 1][i & 1];
                v[i] = a + __shfl_xor(a, 32, 64);
            }
            if (lane < 32) {
#pragma unroll
                for (int i = 0; i < 16; ++i)
                    red[w][lane * 17 + ((i + lane) & 15)] = v[i];
            }
            __syncthreads();
            if (lane < 16) {
                int s = 0;
#pragma unroll
                for (int l = 0; l < 32; ++l)
                    s += red[w][l * 17 + ((lane + l) & 15)];
                const int r   = lane >> 1;          // 0..7
                const int b   = lane & 1;
                const int row = rbase + r;
                const int bg  = b0 + b;
                // dequant: W ~ wq*s_r, h ~ hq/127
                float pre = (float)s * wscale[w * 8 + r] * (1.f / 127.f);
#pragma unroll
                for (int c = 0; c < NIN; ++c)
                    pre += Win[row * NIN + c] * x[((size_t)bg * TSTEPS + t) * NIN + c];
                hblk[w * 8 + r][b] = tanhf(pre);
            }
            __syncthreads();   // hblk complete

            // ---- write h_new strips int8 (UC) + flag, r8-exact discipline ----
            if (w == 0) {
                if (lane < 32) {
                    const int b = lane >> 4;        // 0..1
                    const int j = lane & 15;        // dword: rows 4j..4j+3
                    unsigned p = pack4(q8(hblk[4 * j][b] * 127.f),
                                       q8(hblk[4 * j + 1][b] * 127.f),
                                       q8(hblk[4 * j + 2][b] * 127.f),
                                       q8(hblk[4 * j + 3][b] * 127.f));
                    sysst((unsigned*)(hnext + (size_t)(b0 + b) * RDIM + rg * 64) + j, p);
                }
                __builtin_amdgcn_s_waitcnt(0);      // strips visible first
            }
            __syncthreads();
            if (tid == 0) sysst(&flags[g * 32 + rg], (unsigned)(t + 1));
        }

        // ---- projection of h_{t-1}-state (int8 in hs) by rotating block ----
        if (t > 0 && rg == ((t - 1) & 31)) {
            const signed char* hsv = (const signed char*)hs_dw;
            const int o = t - 1;
            if (w < 6) {
                const int b = w / NOUT;             // 0..1
                const int k = w % NOUT;             // 0..2
                float a = 0.f;
#pragma unroll
                for (int j = 0; j < 32; ++j) {
                    const int r = j * 64 + lane;
                    a += (float)hsv[b * RDIM + r] * Wout[k * RDIM + r];
                }
#pragma unroll
                for (int off = 32; off >= 1; off >>= 1)
                    a += __shfl_xor(a, off, 64);
                if (lane == 0)
                    out[((size_t)(b0 + b) * TSTEPS + o) * NOUT + k] =
                        a * (1.f / 127.f) + bout[k];
            }
        }
    }
}

extern "C" void kernel_launch(void* const* d_in, const int* in_sizes, int n_in,
                              void* d_out, int out_size, void* d_ws, size_t ws_size,
                              hipStream_t stream) {
    const float* x    = (const float*)d_in[0];
    const float* Win  = (const float*)d_in[1];
    const float* W    = (const float*)d_in[2];
    const float* Wout = (const float*)d_in[3];
    const float* bout = (const float*)d_in[4];
    float* out = (float*)d_out;

    unsigned char* wsb = (unsigned char*)d_ws;
    unsigned char* hb0 = wsb + OFF_H0_B;
    unsigned char* hb1 = wsb + OFF_H1_B;
    unsigned*    flags = (unsigned*)d_ws + OFF_FLAGS;

    // zero h buffers (h0 = 0 in int8 too) + flags (~66 KB)
    hipMemsetAsync(d_ws, 0, (size_t)WS_USED_DW * sizeof(unsigned), stream);

    // allow 128 KB dynamic LDS (idempotent; same work every call)
    hipFuncSetAttribute((const void*)esn_persist,
                        hipFuncAttributeMaxDynamicSharedMemorySize, 131072);

    void* args[] = {(void*)&W, (void*)&Win, (void*)&x, (void*)&Wout, (void*)&bout,
                    (void*)&hb0, (void*)&hb1, (void*)&flags, (void*)&out};
    hipError_t e = hipLaunchCooperativeKernel((const void*)esn_persist,
                                              dim3(NBLK), dim3(NTHR),
                                              args, 131072, stream);
    if (e != hipSuccess) {
        // Fallback: plain launch (256 blocks, 1/CU with ~150KB LDS -> all
        // co-resident; bounded spins guarantee no hang regardless).
        esn_persist<<<dim3(NBLK), dim3(NTHR), 131072, stream>>>(
            W, Win, x, Wout, bout, hb0, hb1, flags, out);
    }
}